// Round 12
// baseline (103.988 us; speedup 1.0000x reference)
//
#include <hip/hip_runtime.h>
#include <hip/hip_bf16.h>
#include <math.h>

#define BB   2
#define NN   8192
#define SS   1024
#define KK   32
#define HID  256
#define NTH  512
#define NWV  8         // waves per block
#define PPT  16        // candidates per thread (NN/NTH)
#define SENT 0xFFFFFFFFFFFFFFFFULL
#define LDB  264       // padded LDS row stride (bf16 elems)
#define WFE  65536     // frag elements per matrix copy (256*256)

typedef unsigned long long u64;
typedef unsigned int       u32;
typedef short bf16x8 __attribute__((ext_vector_type(8)));
typedef float f32x4  __attribute__((ext_vector_type(4)));

// sorted-4 insertion: compare-swap carry chain (keeps s0..s3 ascending, drops max)
#define CSW(SI) { const u64 mn = x < (SI) ? x : (SI); const u64 mx = x < (SI) ? (SI) : x; (SI) = mn; x = mx; }
#define INS(KV) { u64 x = (KV); CSW(s0) CSW(s1) CSW(s2) CSW(s3) }

// tanh via hardware exp/rcp: tanh(y) = 1 - 2/(1+e^{2y}); saturates correctly.
__device__ __forceinline__ float tanh_fast(float y) {
    const float e = __expf(2.0f * y);
    const float r = __builtin_amdgcn_rcpf(e + 1.0f);
    return fmaf(-2.0f, r, 1.0f);
}

__device__ __forceinline__ short bf_bits(float f) {
    const __hip_bfloat16 h = __float2bfloat16(f);   // RNE
    short s;
    __builtin_memcpy(&s, &h, 2);
    return s;
}

// popcount of mask restricted to lanes below me
__device__ __forceinline__ int mbcnt64(u64 m) {
    return (int)__builtin_amdgcn_mbcnt_hi((u32)(m >> 32),
           __builtin_amdgcn_mbcnt_lo((u32)m, 0u));
}

// ---- prep: split w1/w2 into bf16 hi+lo, MFMA B-frag order, ks-major grouping ----
// elem slot = mat*131072 + (((ks*16+ntg)*2+hl)*64+lane)*8 + j
// element  = W[k][n], k = ks*32 + (lane>>4)*8 + j, n = ntg*16 + (lane&15)
__global__ void prep_w(const float* __restrict__ w1, const float* __restrict__ w2,
                       __hip_bfloat16* __restrict__ wf) {
    const int idx = blockIdx.x * 256 + threadIdx.x;   // 0..131071
    const int j   = idx & 7;
    const int l   = (idx >> 3) & 63;
    const int ntg = (idx >> 9) & 15;
    const int ks  = (idx >> 13) & 7;
    const int mat = idx >> 16;
    const int k = ks * 32 + (l >> 4) * 8 + j;
    const int n = ntg * 16 + (l & 15);
    const float v = (mat ? w2 : w1)[k * HID + n];
    const __hip_bfloat16 hi = __float2bfloat16(v);
    const float res = v - __bfloat162float(hi);
    const size_t s0 = (size_t)mat * 131072 + ((size_t)((ks*16 + ntg)*2) * 64 + l) * 8 + j;
    wf[s0]       = hi;
    wf[s0 + 512] = __float2bfloat16(res);            // hl=1 slot
}

__global__ __launch_bounds__(NTH, 8)
void snp_kernel(const float* __restrict__ pos,     // (B,N,3)
                const int*   __restrict__ snidx,   // (S,)
                const float* __restrict__ w_in,    // (3,HID)
                const float* __restrict__ b_in,    // (HID,)
                const float* __restrict__ b1,      // (HID,)
                const float* __restrict__ b2,      // (HID,)
                const __hip_bfloat16* __restrict__ wf,  // frag-packed w1/w2 hi+lo
                float*       __restrict__ out)     // (B,S,HID)
{
    const int bs   = blockIdx.x;        // 0 .. B*S-1
    const int b    = bs / SS;
    const int s    = bs - b * SS;
    const int t    = threadIdx.x;
    const int lane = t & 63;
    const int wv   = t >> 6;

    __shared__ __align__(16) short h0b[KK][LDB];   // bf16 activations (16896 B)
    __shared__ u64   wl[NWV * KK];                 // 8 waves x 32 selected keys
    __shared__ int   nbr[KK];
    __shared__ __align__(16) float nbc[4 * KK];    // float4-strided coords

    const float* posb = pos + (size_t)b * (NN * 3);
    const int   sp = snidx[s];
    const float sx = posb[sp*3 + 0];
    const float sy = posb[sp*3 + 1];
    const float sz = posb[sp*3 + 2];

    // ---- Phase 1: stream distances (reference rounding), per-lane sorted top-4 ----
    // Key: (distbits << 13) | idx — order == (dist, idx) lex; all keys distinct.
    u64 s0=SENT,s1=SENT,s2=SENT,s3=SENT;
#pragma unroll 4
    for (int c = 0; c < PPT; ++c) {
        const int i = c * NTH + t;                 // coalesced across lanes
        const float dx = __fsub_rn(sx, posb[i*3 + 0]);
        const float dy = __fsub_rn(sy, posb[i*3 + 1]);
        const float dz = __fsub_rn(sz, posb[i*3 + 2]);
        const float sq = __fadd_rn(__fadd_rn(__fmul_rn(dx,dx), __fmul_rn(dy,dy)),
                                   __fmul_rn(dz,dz));
        const u64 kv = ((u64)__float_as_uint(__fsqrt_rn(sq)) << 13) | (u32)i;
        INS(kv);
    }

    // ---- Phase 2: wave-level threshold selection (ballot binary search) ----
    {
        u64 L = 0;
        for (int bit = 43; bit >= 13; --bit) {     // distbit part first
            const u64 cand = L | (1ull << bit);
            const int cnt = __popcll(__ballot(s0 < cand)) + __popcll(__ballot(s1 < cand))
                          + __popcll(__ballot(s2 < cand)) + __popcll(__ballot(s3 < cand));
            if (cnt < 32) L = cand;
        }
        u64 TH = L + (1ull << 13);                 // candidate cut: distbits <= D
        {
            const int cnt = __popcll(__ballot(s0 < TH)) + __popcll(__ballot(s1 < TH))
                          + __popcll(__ballot(s2 < TH)) + __popcll(__ballot(s3 < TH));
            if (cnt != 32) {                       // distbit tie at cut: resolve by idx
                for (int bit = 12; bit >= 0; --bit) {
                    const u64 cand = L | (1ull << bit);
                    const int c2 = __popcll(__ballot(s0 < cand)) + __popcll(__ballot(s1 < cand))
                                 + __popcll(__ballot(s2 < cand)) + __popcll(__ballot(s3 < cand));
                    if (c2 < 32) L = cand;
                }
                TH = L + 1;                        // select = key <= L
            }
        }
        const bool b0 = s0 < TH, b1 = s1 < TH, b2 = s2 < TH, b3 = s3 < TH;
        const int csel = (int)b0 + (int)b1 + (int)b2 + (int)b3;

        if (__ballot(csel == 4) != 0ull) {
            // Saturated lane (possible hidden 5th key < TH): proven serial fallback.
            int nv = 4;
#pragma unroll 1
            for (int it = 0; it < KK; ++it) {
                u64 m = s0;
#pragma unroll
                for (int off = 32; off > 0; off >>= 1) {
                    const u64 o = __shfl_xor(m, off, 64);
                    m = o < m ? o : m;
                }
                if (lane == 0) wl[wv*KK + it] = m;
                if (s0 == m) {
                    s0=s1; s1=s2; s2=s3; s3=SENT;
                    if (--nv == 0) {                // refill from stream, keys > m
                        const u64 last = m;
                        s0=s1=s2=s3=SENT;
#pragma unroll 4
                        for (int c = 0; c < PPT; ++c) {
                            const int i = c * NTH + t;
                            const float dx = __fsub_rn(sx, posb[i*3 + 0]);
                            const float dy = __fsub_rn(sy, posb[i*3 + 1]);
                            const float dz = __fsub_rn(sz, posb[i*3 + 2]);
                            const float sq = __fadd_rn(__fadd_rn(__fmul_rn(dx,dx), __fmul_rn(dy,dy)),
                                                       __fmul_rn(dz,dz));
                            u64 kv = ((u64)__float_as_uint(__fsqrt_rn(sq)) << 13) | (u32)i;
                            kv = kv > last ? kv : SENT;
                            INS(kv);
                        }
                        nv = (int)(s0!=SENT)+(int)(s1!=SENT)+(int)(s2!=SENT)+(int)(s3!=SENT);
                    }
                }
            }
        } else {
            // Exact-32 fast path: compact selected keys (unsorted; order irrelevant).
            const u64 m0 = __ballot(b0), m1 = __ballot(b1),
                      m2 = __ballot(b2), m3 = __ballot(b3);
            const int pos2 = mbcnt64(m0) + mbcnt64(m1) + mbcnt64(m2) + mbcnt64(m3);
            u64* wwl = &wl[wv * KK];
            if (b0) wwl[pos2]     = s0;
            if (b1) wwl[pos2 + 1] = s1;
            if (b2) wwl[pos2 + 2] = s2;
            if (b3) wwl[pos2 + 3] = s3;
        }
    }
    __syncthreads();

    // ---- Phase 2b: block stage — top-32 of the 256 wave-selected keys ----
    if (t < 64) {
        const u64 k0 = wl[lane],       k1 = wl[64 + lane];
        const u64 k2 = wl[128 + lane], k3 = wl[192 + lane];
        u64 L = 0;
        for (int bit = 43; bit >= 13; --bit) {
            const u64 cand = L | (1ull << bit);
            const int cnt = __popcll(__ballot(k0 < cand)) + __popcll(__ballot(k1 < cand))
                          + __popcll(__ballot(k2 < cand)) + __popcll(__ballot(k3 < cand));
            if (cnt < 32) L = cand;
        }
        u64 TH = L + (1ull << 13);
        {
            const int cnt = __popcll(__ballot(k0 < TH)) + __popcll(__ballot(k1 < TH))
                          + __popcll(__ballot(k2 < TH)) + __popcll(__ballot(k3 < TH));
            if (cnt != 32) {
                for (int bit = 12; bit >= 0; --bit) {
                    const u64 cand = L | (1ull << bit);
                    const int c2 = __popcll(__ballot(k0 < cand)) + __popcll(__ballot(k1 < cand))
                                 + __popcll(__ballot(k2 < cand)) + __popcll(__ballot(k3 < cand));
                    if (c2 < 32) L = cand;
                }
                TH = L + 1;
            }
        }
        const bool c0 = k0 < TH, c1 = k1 < TH, c2 = k2 < TH, c3 = k3 < TH;
        const int p = mbcnt64(__ballot(c0)) + mbcnt64(__ballot(c1))
                    + mbcnt64(__ballot(c2)) + mbcnt64(__ballot(c3));
        int q = p;
        if (c0) { nbr[q] = (int)(k0 & 8191u); ++q; }
        if (c1) { nbr[q] = (int)(k1 & 8191u); ++q; }
        if (c2) { nbr[q] = (int)(k2 & 8191u); ++q; }
        if (c3) { nbr[q] = (int)(k3 & 8191u); }
    }
    __syncthreads();

    // ---- Phase 3: gather neighbor coords (float4-strided for b128 reads) ----
    if (t < KK * 3) {
        const int k = t / 3, d = t - 3 * k;
        nbc[k * 4 + d] = posb[(size_t)nbr[k] * 3 + d];
    }
    __syncthreads();

    // ---- Phase 4: h0 = coords @ w_in + b_in + sincos PE -> bf16 ----
    // thread = (channel c = t&255, half = t>>8); each computes 16 k-rows.
    {
        const int  c     = t & 255;
        const int  kh    = (t >> 8) * 16;           // 0 or 16
        const int  dimi  = c / 84;                  // 84 = 2*42 channels per dim
        const int  cc    = c - dimi * 84;
        const bool hasPe = c < 252;
        const bool isCos = cc >= 42;
        const int  f     = isCos ? cc - 42 : cc;
        const float fcoef = (float)(-9.210340371976184 / 41.0);
        const float freqv = expf((float)f * fcoef);
        const int  di    = hasPe ? dimi : 0;

        const float wi0 = w_in[0*HID + c];
        const float wi1 = w_in[1*HID + c];
        const float wi2 = w_in[2*HID + c];
        const float bi  = b_in[c];

#pragma unroll 4
        for (int kk = 0; kk < 16; ++kk) {
            const int k = kh + kk;
            const float4 xv4 = *(const float4*)&nbc[k * 4];   // one b128 read
            const float x0 = xv4.x, x1 = xv4.y, x2 = xv4.z;
            float v = fmaf(x2, wi2, fmaf(x1, wi1, fmaf(x0, wi0, bi)));
            if (hasPe) {
                const float xv  = (di == 0) ? x0 : ((di == 1) ? x1 : x2);
                const float ang = xv * freqv;
                v += isCos ? __cosf(ang) : __sinf(ang);   // native (args |x|<~6)
            }
            h0b[k][c] = bf_bits(v);
        }
    }
    __syncthreads();

    // ---- MLP via bf16 MFMA, split weights (hi+lo); wave owns 32 channels ----
    // A frag (16x16x32): row = lane&15, k = ks*32 + (lane>>4)*8 + j  (matches prep).
    // C/D: col = lane&15, row = (lane>>4)*4 + reg   [HW-verified m89]
    const int lr = lane & 15;
    const int lg = lane >> 4;
    const int nbase = wv * 32;                     // ntg = wv*2 + nt

    const short* arow0 = &h0b[lr][lg * 8];
    const short* arow1 = &h0b[16 + lr][lg * 8];
    // weight slot = mat*131072 + ks*16384 + ntg*1024 + hl*512 + lane*8
    const __hip_bfloat16* wb1 = wf + (size_t)wv * 2048 + lane * 8;
    const __hip_bfloat16* wb2 = wb1 + 2 * WFE;

    f32x4 acc[2][2];

    // ---- layer 1: h1 = h0 @ w1 + b1 ----
    {
#pragma unroll
        for (int nt = 0; nt < 2; ++nt) {
            const float bias = b1[nbase + nt*16 + lr];
            const f32x4 bv = {bias, bias, bias, bias};
            acc[0][nt] = bv; acc[1][nt] = bv;
        }
#pragma unroll 1
        for (int ks = 0; ks < 8; ++ks) {
            const bf16x8 af0 = *(const bf16x8*)(arow0 + ks * 32);
            const bf16x8 af1 = *(const bf16x8*)(arow1 + ks * 32);
            const __hip_bfloat16* p = wb1 + ks * 16384;
#pragma unroll
            for (int nt = 0; nt < 2; ++nt) {
                const bf16x8 bh = *(const bf16x8*)(p + nt * 1024);
                acc[0][nt] = __builtin_amdgcn_mfma_f32_16x16x32_bf16(af0, bh, acc[0][nt], 0,0,0);
                acc[1][nt] = __builtin_amdgcn_mfma_f32_16x16x32_bf16(af1, bh, acc[1][nt], 0,0,0);
                const bf16x8 bl = *(const bf16x8*)(p + nt * 1024 + 512);
                acc[0][nt] = __builtin_amdgcn_mfma_f32_16x16x32_bf16(af0, bl, acc[0][nt], 0,0,0);
                acc[1][nt] = __builtin_amdgcn_mfma_f32_16x16x32_bf16(af1, bl, acc[1][nt], 0,0,0);
            }
        }
    }
    __syncthreads();                                 // all layer-1 h0 reads done

    // gelu (tanh approx) -> h0b (bf16; same rounding as before)
    {
        const float kA = 0.7978845608028654f;        // sqrt(2/pi)
#pragma unroll
        for (int mt = 0; mt < 2; ++mt)
#pragma unroll
        for (int nt = 0; nt < 2; ++nt)
#pragma unroll
        for (int r = 0; r < 4; ++r) {
            const float x  = acc[mt][nt][r];
            const float x3 = x * x * x;
            const float tv = tanh_fast(kA * fmaf(0.044715f, x3, x));
            h0b[mt*16 + lg*4 + r][nbase + nt*16 + lr] = bf_bits(0.5f * x * (1.0f + tv));
        }
    }
    __syncthreads();

    // ---- layer 2: g @ w2 (bias+mean folded into epilogue) ----
    {
        const f32x4 z = {0.f, 0.f, 0.f, 0.f};
#pragma unroll
        for (int nt = 0; nt < 2; ++nt) { acc[0][nt] = z; acc[1][nt] = z; }
#pragma unroll 1
        for (int ks = 0; ks < 8; ++ks) {
            const bf16x8 af0 = *(const bf16x8*)(arow0 + ks * 32);
            const bf16x8 af1 = *(const bf16x8*)(arow1 + ks * 32);
            const __hip_bfloat16* p = wb2 + ks * 16384;
#pragma unroll
            for (int nt = 0; nt < 2; ++nt) {
                const bf16x8 bh = *(const bf16x8*)(p + nt * 1024);
                acc[0][nt] = __builtin_amdgcn_mfma_f32_16x16x32_bf16(af0, bh, acc[0][nt], 0,0,0);
                acc[1][nt] = __builtin_amdgcn_mfma_f32_16x16x32_bf16(af1, bh, acc[1][nt], 0,0,0);
                const bf16x8 bl = *(const bf16x8*)(p + nt * 1024 + 512);
                acc[0][nt] = __builtin_amdgcn_mfma_f32_16x16x32_bf16(af0, bl, acc[0][nt], 0,0,0);
                acc[1][nt] = __builtin_amdgcn_mfma_f32_16x16x32_bf16(af1, bl, acc[1][nt], 0,0,0);
            }
        }
    }

    // ---- epilogue: mean over 32 rows + b2; lanes<16 write the wave's 32 channels ----
#pragma unroll
    for (int nt = 0; nt < 2; ++nt) {
        float ssum = 0.0f;
#pragma unroll
        for (int mt = 0; mt < 2; ++mt)
#pragma unroll
            for (int r = 0; r < 4; ++r) ssum += acc[mt][nt][r];
        ssum += __shfl_xor(ssum, 16, 64);            // sum over lane-groups
        ssum += __shfl_xor(ssum, 32, 64);
        if (lane < 16) {
            const int ch = nbase + nt*16 + lane;
            out[(size_t)bs * HID + ch] = fmaf(ssum, 1.0f / KK, b2[ch]);
        }
    }
}

extern "C" void kernel_launch(void* const* d_in, const int* in_sizes, int n_in,
                              void* d_out, int out_size, void* d_ws, size_t ws_size,
                              hipStream_t stream) {
    const float* pos  = (const float*)d_in[0];
    const int*   sni  = (const int*)  d_in[1];
    const float* w_in = (const float*)d_in[2];
    const float* b_in = (const float*)d_in[3];
    const float* w1   = (const float*)d_in[4];
    const float* b1   = (const float*)d_in[5];
    const float* w2   = (const float*)d_in[6];
    const float* b2   = (const float*)d_in[7];
    float* out = (float*)d_out;
    __hip_bfloat16* wf = (__hip_bfloat16*)d_ws;      // 4*65536*2B = 512 KB
    (void)ws_size; (void)in_sizes; (void)n_in; (void)out_size;

    hipLaunchKernelGGL(prep_w, dim3(2 * WFE / 256), dim3(256), 0, stream, w1, w2, wf);
    hipLaunchKernelGGL(snp_kernel, dim3(BB * SS), dim3(NTH), 0, stream,
                       pos, sni, w_in, b_in, b1, b2, wf, out);
}

// Round 13
// 86.399 us; speedup vs baseline: 1.2036x; 1.2036x over previous
//
#include <hip/hip_runtime.h>
#include <hip/hip_bf16.h>
#include <math.h>

#define BB   2
#define NN   8192
#define SS   1024
#define KK   32
#define HID  256
#define NTH  256
#define PPT  64        // candidates per thread (NN / 128 lanes-per-token)
#define SENT 0xFFFFFFFFFFFFFFFFULL
#define LDB  264       // padded LDS row stride (bf16 elems); 528B rows, 16B aligned
#define WFE  65536     // frag elements per matrix copy (256*256)

typedef unsigned long long u64;
typedef unsigned int       u32;
typedef short bf16x8 __attribute__((ext_vector_type(8)));
typedef float f32x4  __attribute__((ext_vector_type(4)));

// sorted-4 insertion: compare-swap carry chain (keeps s0..s3 ascending, drops max)
#define CSW(SI) { const u64 mn = x < (SI) ? x : (SI); const u64 mx = x < (SI) ? (SI) : x; (SI) = mn; x = mx; }
#define INS(KV) { u64 x = (KV); CSW(s0) CSW(s1) CSW(s2) CSW(s3) }

// tanh via hardware exp/rcp: tanh(y) = 1 - 2/(1+e^{2y}); saturates correctly.
__device__ __forceinline__ float tanh_fast(float y) {
    const float e = __expf(2.0f * y);
    const float r = __builtin_amdgcn_rcpf(e + 1.0f);
    return fmaf(-2.0f, r, 1.0f);
}

__device__ __forceinline__ short bf_bits(float f) {
    const __hip_bfloat16 h = __float2bfloat16(f);   // RNE
    short s;
    __builtin_memcpy(&s, &h, 2);
    return s;
}

// popcount of mask restricted to lanes below me
__device__ __forceinline__ int mbcnt64(u64 m) {
    return (int)__builtin_amdgcn_mbcnt_hi((u32)(m >> 32),
           __builtin_amdgcn_mbcnt_lo((u32)m, 0u));
}

// ---- prep: split w1/w2 into bf16 hi+lo, MFMA B-frag order, ks-major grouping ----
// elem slot = mat*131072 + (((ks*16+ntg)*2+hl)*64+lane)*8 + j
// element  = W[k][n], k = ks*32 + (lane>>4)*8 + j, n = ntg*16 + (lane&15)
__global__ void prep_w(const float* __restrict__ w1, const float* __restrict__ w2,
                       __hip_bfloat16* __restrict__ wf) {
    const int idx = blockIdx.x * 256 + threadIdx.x;   // 0..131071
    const int j   = idx & 7;
    const int l   = (idx >> 3) & 63;
    const int ntg = (idx >> 9) & 15;
    const int ks  = (idx >> 13) & 7;
    const int mat = idx >> 16;
    const int k = ks * 32 + (l >> 4) * 8 + j;
    const int n = ntg * 16 + (l & 15);
    const float v = (mat ? w2 : w1)[k * HID + n];
    const __hip_bfloat16 hi = __float2bfloat16(v);
    const float res = v - __bfloat162float(hi);
    const size_t s0 = (size_t)mat * 131072 + ((size_t)((ks*16 + ntg)*2) * 64 + l) * 8 + j;
    wf[s0]       = hi;
    wf[s0 + 512] = __float2bfloat16(res);            // hl=1 slot
}

// One block handles TWO supernode tokens (same batch b): waves 0-1 do KNN for
// token A, waves 2-3 for token B; the MLP is one M=64 GEMM so each weight
// fragment load feeds 4 MFMAs (halves L2 weight traffic vs 1 token/block).
__global__ __launch_bounds__(NTH, 4)
void snp_kernel(const float* __restrict__ pos,     // (B,N,3)
                const int*   __restrict__ snidx,   // (S,)
                const float* __restrict__ w_in,    // (3,HID)
                const float* __restrict__ b_in,    // (HID,)
                const float* __restrict__ b1,      // (HID,)
                const float* __restrict__ b2,      // (HID,)
                const __hip_bfloat16* __restrict__ wf,  // frag-packed w1/w2 hi+lo
                float*       __restrict__ out)     // (B,S,HID)
{
    const int tk0  = blockIdx.x * 2;    // first token (b*SS + s), same b for both
    const int b    = tk0 / SS;
    const int s0i  = tk0 - b * SS;
    const int t    = threadIdx.x;
    const int lane = t & 63;
    const int wv   = t >> 6;
    const int tok  = t >> 7;            // waves 0-1 -> token 0; waves 2-3 -> token 1
    const int pl   = t & 127;           // lane within the token's 128-thread group

    __shared__ __align__(16) short h0b[2 * KK][LDB]; // bf16 activations (33792 B)
    __shared__ u64   wl[4 * KK];                     // 4 waves x 32 selected keys
    __shared__ int   nbr[2 * KK];
    __shared__ __align__(16) float nbc[2 * 4 * KK];  // float4-strided coords

    const float* posb = pos + (size_t)b * (NN * 3);
    const int  spA = snidx[s0i], spB = snidx[s0i + 1];
    const int  sp  = tok ? spB : spA;
    const float sx = posb[sp*3 + 0];
    const float sy = posb[sp*3 + 1];
    const float sz = posb[sp*3 + 2];

    // ---- Phase 1: stream distances (reference rounding), per-lane sorted top-4 ----
    // Key: (distbits << 13) | idx — order == (dist, idx) lex; all keys distinct.
    u64 s0=SENT,s1=SENT,s2=SENT,s3=SENT;
#pragma unroll 4
    for (int c = 0; c < PPT; ++c) {
        const int i = c * 128 + pl;                // each token group covers all NN
        const float dx = __fsub_rn(sx, posb[i*3 + 0]);
        const float dy = __fsub_rn(sy, posb[i*3 + 1]);
        const float dz = __fsub_rn(sz, posb[i*3 + 2]);
        const float sq = __fadd_rn(__fadd_rn(__fmul_rn(dx,dx), __fmul_rn(dy,dy)),
                                   __fmul_rn(dz,dz));
        const u64 kv = ((u64)__float_as_uint(__fsqrt_rn(sq)) << 13) | (u32)i;
        INS(kv);
    }

    // ---- Phase 2: wave-level threshold selection (ballot binary search) ----
    {
        u64 L = 0;
        for (int bit = 43; bit >= 13; --bit) {     // distbit part first
            const u64 cand = L | (1ull << bit);
            const int cnt = __popcll(__ballot(s0 < cand)) + __popcll(__ballot(s1 < cand))
                          + __popcll(__ballot(s2 < cand)) + __popcll(__ballot(s3 < cand));
            if (cnt < 32) L = cand;
        }
        u64 TH = L + (1ull << 13);                 // candidate cut: distbits <= D
        {
            const int cnt = __popcll(__ballot(s0 < TH)) + __popcll(__ballot(s1 < TH))
                          + __popcll(__ballot(s2 < TH)) + __popcll(__ballot(s3 < TH));
            if (cnt != 32) {                       // distbit tie at cut: resolve by idx
                for (int bit = 12; bit >= 0; --bit) {
                    const u64 cand = L | (1ull << bit);
                    const int c2 = __popcll(__ballot(s0 < cand)) + __popcll(__ballot(s1 < cand))
                                 + __popcll(__ballot(s2 < cand)) + __popcll(__ballot(s3 < cand));
                    if (c2 < 32) L = cand;
                }
                TH = L + 1;                        // select = key <= L
            }
        }
        const bool b0 = s0 < TH, b1 = s1 < TH, b2 = s2 < TH, b3 = s3 < TH;
        const int csel = (int)b0 + (int)b1 + (int)b2 + (int)b3;

        if (__ballot(csel == 4) != 0ull) {
            // Saturated lane (possible hidden 5th key < TH): proven serial fallback.
            int nv = 4;
#pragma unroll 1
            for (int it = 0; it < KK; ++it) {
                u64 m = s0;
#pragma unroll
                for (int off = 32; off > 0; off >>= 1) {
                    const u64 o = __shfl_xor(m, off, 64);
                    m = o < m ? o : m;
                }
                if (lane == 0) wl[wv*KK + it] = m;
                if (s0 == m) {
                    s0=s1; s1=s2; s2=s3; s3=SENT;
                    if (--nv == 0) {                // refill from stream, keys > m
                        const u64 last = m;
                        s0=s1=s2=s3=SENT;
#pragma unroll 4
                        for (int c = 0; c < PPT; ++c) {
                            const int i = c * 128 + pl;
                            const float dx = __fsub_rn(sx, posb[i*3 + 0]);
                            const float dy = __fsub_rn(sy, posb[i*3 + 1]);
                            const float dz = __fsub_rn(sz, posb[i*3 + 2]);
                            const float sq = __fadd_rn(__fadd_rn(__fmul_rn(dx,dx), __fmul_rn(dy,dy)),
                                                       __fmul_rn(dz,dz));
                            u64 kv = ((u64)__float_as_uint(__fsqrt_rn(sq)) << 13) | (u32)i;
                            kv = kv > last ? kv : SENT;
                            INS(kv);
                        }
                        nv = (int)(s0!=SENT)+(int)(s1!=SENT)+(int)(s2!=SENT)+(int)(s3!=SENT);
                    }
                }
            }
        } else {
            // Exact-32 fast path: compact selected keys (unsorted; order irrelevant).
            const u64 m0 = __ballot(b0), m1 = __ballot(b1),
                      m2 = __ballot(b2), m3 = __ballot(b3);
            const int pos2 = mbcnt64(m0) + mbcnt64(m1) + mbcnt64(m2) + mbcnt64(m3);
            u64* wwl = &wl[wv * KK];
            if (b0) wwl[pos2]     = s0;
            if (b1) wwl[pos2 + 1] = s1;
            if (b2) wwl[pos2 + 2] = s2;
            if (b3) wwl[pos2 + 3] = s3;
        }
    }
    __syncthreads();

    // ---- Phase 2b: per-token block stage — top-32 of 64 keys, 1 key/lane ----
    // Wave 0 -> token 0 (wl[0..63]); wave 1 -> token 1 (wl[64..127]).
    if (t < 128) {
        const u64 k0 = wl[wv * 64 + lane];
        u64 L = 0;
        for (int bit = 43; bit >= 13; --bit) {
            const u64 cand = L | (1ull << bit);
            if (__popcll(__ballot(k0 < cand)) < 32) L = cand;
        }
        u64 TH = L + (1ull << 13);
        if (__popcll(__ballot(k0 < TH)) != 32) {
            for (int bit = 12; bit >= 0; --bit) {
                const u64 cand = L | (1ull << bit);
                if (__popcll(__ballot(k0 < cand)) < 32) L = cand;
            }
            TH = L + 1;
        }
        const bool c0 = k0 < TH;                   // exactly 32 lanes selected
        const int p = mbcnt64(__ballot(c0));
        if (c0) nbr[wv * KK + p] = (int)(k0 & 8191u);
    }
    __syncthreads();

    // ---- Phase 3: gather neighbor coords (float4-strided for b128 reads) ----
    if (t < 2 * KK * 3) {
        const int k = t / 3, d = t - 3 * k;        // k in [0,64): row (token*32+kk)
        nbc[k * 4 + d] = posb[(size_t)nbr[k] * 3 + d];
    }
    __syncthreads();

    // ---- Phase 4: h0 = coords @ w_in + b_in + sincos PE -> bf16 (thread = channel) ----
    {
        const int  c     = t;
        const int  dimi  = c / 84;                  // 84 = 2*42 channels per dim
        const int  cc    = c - dimi * 84;
        const bool hasPe = c < 252;
        const bool isCos = cc >= 42;
        const int  f     = isCos ? cc - 42 : cc;
        const float fcoef = (float)(-9.210340371976184 / 41.0);
        const float freqv = expf((float)f * fcoef);
        const int  di    = hasPe ? dimi : 0;

        const float wi0 = w_in[0*HID + c];
        const float wi1 = w_in[1*HID + c];
        const float wi2 = w_in[2*HID + c];
        const float bi  = b_in[c];

#pragma unroll 4
        for (int k = 0; k < 2 * KK; ++k) {         // 64 rows (2 tokens x 32)
            const float4 xv4 = *(const float4*)&nbc[k * 4];   // one b128 read
            const float x0 = xv4.x, x1 = xv4.y, x2 = xv4.z;
            float v = fmaf(x2, wi2, fmaf(x1, wi1, fmaf(x0, wi0, bi)));
            if (hasPe) {
                const float xv  = (di == 0) ? x0 : ((di == 1) ? x1 : x2);
                const float ang = xv * freqv;
                v += isCos ? __cosf(ang) : __sinf(ang);   // native (args |x|<~6)
            }
            h0b[k][c] = bf_bits(v);
        }
    }
    __syncthreads();

    // ---- MLP via bf16 MFMA, split weights (hi+lo); M=64, wave owns 64 channels ----
    // A frag (16x16x32): row = lane&15, k = ks*32 + (lane>>4)*8 + j  (matches prep).
    // C/D: col = lane&15, row = (lane>>4)*4 + reg   [HW-verified m89]
    const int lr = lane & 15;
    const int lg = lane >> 4;
    const int nbase = wv * 64;

    const short* arow0 = &h0b[lr][lg * 8];
    const short* arow1 = &h0b[16 + lr][lg * 8];
    const short* arow2 = &h0b[32 + lr][lg * 8];
    const short* arow3 = &h0b[48 + lr][lg * 8];
    // weight slot = mat*131072 + ks*16384 + ntg*1024 + hl*512 + lane*8 ; ntg = wv*4+nt
    const __hip_bfloat16* wb1 = wf + (size_t)wv * 4096 + lane * 8;
    const __hip_bfloat16* wb2 = wb1 + 2 * WFE;

    f32x4 acc[4][4];

    // ---- layer 1: h1 = h0 @ w1 + b1 ----
    {
#pragma unroll
        for (int nt = 0; nt < 4; ++nt) {
            const float bias = b1[nbase + nt*16 + lr];
            const f32x4 bv = {bias, bias, bias, bias};
            acc[0][nt] = bv; acc[1][nt] = bv; acc[2][nt] = bv; acc[3][nt] = bv;
        }
#pragma unroll 1
        for (int ks = 0; ks < 8; ++ks) {
            const bf16x8 af0 = *(const bf16x8*)(arow0 + ks * 32);
            const bf16x8 af1 = *(const bf16x8*)(arow1 + ks * 32);
            const bf16x8 af2 = *(const bf16x8*)(arow2 + ks * 32);
            const bf16x8 af3 = *(const bf16x8*)(arow3 + ks * 32);
            const __hip_bfloat16* p = wb1 + ks * 16384;
#pragma unroll
            for (int nt = 0; nt < 4; ++nt) {
                const bf16x8 bh = *(const bf16x8*)(p + nt * 1024);
                acc[0][nt] = __builtin_amdgcn_mfma_f32_16x16x32_bf16(af0, bh, acc[0][nt], 0,0,0);
                acc[1][nt] = __builtin_amdgcn_mfma_f32_16x16x32_bf16(af1, bh, acc[1][nt], 0,0,0);
                acc[2][nt] = __builtin_amdgcn_mfma_f32_16x16x32_bf16(af2, bh, acc[2][nt], 0,0,0);
                acc[3][nt] = __builtin_amdgcn_mfma_f32_16x16x32_bf16(af3, bh, acc[3][nt], 0,0,0);
                const bf16x8 bl = *(const bf16x8*)(p + nt * 1024 + 512);
                acc[0][nt] = __builtin_amdgcn_mfma_f32_16x16x32_bf16(af0, bl, acc[0][nt], 0,0,0);
                acc[1][nt] = __builtin_amdgcn_mfma_f32_16x16x32_bf16(af1, bl, acc[1][nt], 0,0,0);
                acc[2][nt] = __builtin_amdgcn_mfma_f32_16x16x32_bf16(af2, bl, acc[2][nt], 0,0,0);
                acc[3][nt] = __builtin_amdgcn_mfma_f32_16x16x32_bf16(af3, bl, acc[3][nt], 0,0,0);
            }
        }
    }
    __syncthreads();                                 // all layer-1 h0 reads done

    // gelu (tanh approx) -> h0b (bf16; same rounding as before)
    {
        const float kA = 0.7978845608028654f;        // sqrt(2/pi)
#pragma unroll
        for (int mt = 0; mt < 4; ++mt)
#pragma unroll
        for (int nt = 0; nt < 4; ++nt)
#pragma unroll
        for (int r = 0; r < 4; ++r) {
            const float x  = acc[mt][nt][r];
            const float x3 = x * x * x;
            const float tv = tanh_fast(kA * fmaf(0.044715f, x3, x));
            h0b[mt*16 + lg*4 + r][nbase + nt*16 + lr] = bf_bits(0.5f * x * (1.0f + tv));
        }
    }
    __syncthreads();

    // ---- layer 2: g @ w2 (bias+mean folded into epilogue) ----
    {
        const f32x4 z = {0.f, 0.f, 0.f, 0.f};
#pragma unroll
        for (int nt = 0; nt < 4; ++nt) {
            acc[0][nt] = z; acc[1][nt] = z; acc[2][nt] = z; acc[3][nt] = z;
        }
#pragma unroll 1
        for (int ks = 0; ks < 8; ++ks) {
            const bf16x8 af0 = *(const bf16x8*)(arow0 + ks * 32);
            const bf16x8 af1 = *(const bf16x8*)(arow1 + ks * 32);
            const bf16x8 af2 = *(const bf16x8*)(arow2 + ks * 32);
            const bf16x8 af3 = *(const bf16x8*)(arow3 + ks * 32);
            const __hip_bfloat16* p = wb2 + ks * 16384;
#pragma unroll
            for (int nt = 0; nt < 4; ++nt) {
                const bf16x8 bh = *(const bf16x8*)(p + nt * 1024);
                acc[0][nt] = __builtin_amdgcn_mfma_f32_16x16x32_bf16(af0, bh, acc[0][nt], 0,0,0);
                acc[1][nt] = __builtin_amdgcn_mfma_f32_16x16x32_bf16(af1, bh, acc[1][nt], 0,0,0);
                acc[2][nt] = __builtin_amdgcn_mfma_f32_16x16x32_bf16(af2, bh, acc[2][nt], 0,0,0);
                acc[3][nt] = __builtin_amdgcn_mfma_f32_16x16x32_bf16(af3, bh, acc[3][nt], 0,0,0);
                const bf16x8 bl = *(const bf16x8*)(p + nt * 1024 + 512);
                acc[0][nt] = __builtin_amdgcn_mfma_f32_16x16x32_bf16(af0, bl, acc[0][nt], 0,0,0);
                acc[1][nt] = __builtin_amdgcn_mfma_f32_16x16x32_bf16(af1, bl, acc[1][nt], 0,0,0);
                acc[2][nt] = __builtin_amdgcn_mfma_f32_16x16x32_bf16(af2, bl, acc[2][nt], 0,0,0);
                acc[3][nt] = __builtin_amdgcn_mfma_f32_16x16x32_bf16(af3, bl, acc[3][nt], 0,0,0);
            }
        }
    }

    // ---- epilogue: per-token mean over 32 rows + b2; lanes<16 write ----
#pragma unroll
    for (int nt = 0; nt < 4; ++nt) {
        float sumA = 0.0f, sumB = 0.0f;
#pragma unroll
        for (int r = 0; r < 4; ++r) {
            sumA += acc[0][nt][r] + acc[1][nt][r];   // rows 0-31  (token 0)
            sumB += acc[2][nt][r] + acc[3][nt][r];   // rows 32-63 (token 1)
        }
        sumA += __shfl_xor(sumA, 16, 64); sumA += __shfl_xor(sumA, 32, 64);
        sumB += __shfl_xor(sumB, 16, 64); sumB += __shfl_xor(sumB, 32, 64);
        if (lane < 16) {
            const int ch = nbase + nt*16 + lane;
            const float bb = b2[ch];
            out[(size_t)tk0 * HID + ch]       = fmaf(sumA, 1.0f / KK, bb);
            out[(size_t)(tk0 + 1) * HID + ch] = fmaf(sumB, 1.0f / KK, bb);
        }
    }
}

extern "C" void kernel_launch(void* const* d_in, const int* in_sizes, int n_in,
                              void* d_out, int out_size, void* d_ws, size_t ws_size,
                              hipStream_t stream) {
    const float* pos  = (const float*)d_in[0];
    const int*   sni  = (const int*)  d_in[1];
    const float* w_in = (const float*)d_in[2];
    const float* b_in = (const float*)d_in[3];
    const float* w1   = (const float*)d_in[4];
    const float* b1   = (const float*)d_in[5];
    const float* w2   = (const float*)d_in[6];
    const float* b2   = (const float*)d_in[7];
    float* out = (float*)d_out;
    __hip_bfloat16* wf = (__hip_bfloat16*)d_ws;      // 4*65536*2B = 512 KB
    (void)ws_size; (void)in_sizes; (void)n_in; (void)out_size;

    hipLaunchKernelGGL(prep_w, dim3(2 * WFE / 256), dim3(256), 0, stream, w1, w2, wf);
    hipLaunchKernelGGL(snp_kernel, dim3(BB * SS / 2), dim3(NTH), 0, stream,
                       pos, sni, w_in, b_in, b1, b2, wf, out);
}